// Round 1
// baseline (1588.462 us; speedup 1.0000x reference)
//
#include <hip/hip_runtime.h>
#include <cstdint>
#include <cstddef>

// Problem constants (from reference)
constexpr int NN   = 50000;          // nodes
constexpr int EE   = 800000;         // edges (before self-loops)
constexpr int ETOT = EE + NN;        // edges + self loops
constexpr int HC   = 128;            // heads * per-head channels
constexpr float SLOPE = 0.2f;        // leaky_relu slope

// ---- monotone float<->uint mapping so uint atomicMax == float max, and
// ---- memset(0) initializes to -inf-equivalent ----
__device__ __forceinline__ unsigned f2key(float f) {
  unsigned b = __float_as_uint(f);
  return (b & 0x80000000u) ? ~b : (b | 0x80000000u);
}
__device__ __forceinline__ float key2f(unsigned k) {
  unsigned b = (k & 0x80000000u) ? (k ^ 0x80000000u) : ~k;
  return __uint_as_float(b);
}

// ---- fused GEMM (xp = X @ W) + per-node attention coefficients ----
// Block: 128 threads (one per output col). Each block does 8 rows.
template <int K>
__global__ __launch_bounds__(128)
void gemm_alpha(const float* __restrict__ X, const float* __restrict__ W,
                const float* __restrict__ atts, const float* __restrict__ attd,
                float* __restrict__ XP, float* __restrict__ AS,
                float* __restrict__ AD) {
  __shared__ float xs[8][K];
  const int c = threadIdx.x;              // 0..127 output column
  const int row0 = blockIdx.x * 8;
  #pragma unroll
  for (int r = 0; r < 8; ++r)
    for (int k = c; k < K; k += 128)
      xs[r][k] = X[(size_t)(row0 + r) * K + k];
  __syncthreads();

  float acc[8];
  #pragma unroll
  for (int r = 0; r < 8; ++r) acc[r] = 0.f;
  for (int k = 0; k < K; ++k) {
    float w = W[k * HC + c];              // coalesced, L2-resident
    #pragma unroll
    for (int r = 0; r < 8; ++r) acc[r] += xs[r][k] * w;
  }

  const float asc = atts[c];
  const float adc = attd[c];
  #pragma unroll
  for (int r = 0; r < 8; ++r) {
    XP[(size_t)(row0 + r) * HC + c] = acc[r];
    float s = acc[r] * asc;
    float d = acc[r] * adc;
    // reduce over the 32 lanes of one head (offsets <32 stay in-head)
    #pragma unroll
    for (int off = 16; off; off >>= 1) {
      s += __shfl_xor(s, off);
      d += __shfl_xor(d, off);
    }
    if ((c & 31) == 0) {
      AS[(row0 + r) * 4 + (c >> 5)] = s;
      AD[(row0 + r) * 4 + (c >> 5)] = d;
    }
  }
}

__device__ __forceinline__ void edge_sd(const int* __restrict__ ei, int e,
                                        int& s, int& d) {
  if (e < EE) { s = ei[e]; d = ei[EE + e]; }
  else        { s = e - EE; d = s; }      // self loop
}

// ---- per-edge logits -> segment max (monotone-uint atomicMax) ----
__global__ __launch_bounds__(256)
void edge_max(const int* __restrict__ ei, const float* __restrict__ AS,
              const float* __restrict__ AD, unsigned* __restrict__ LM) {
  int e = blockIdx.x * 256 + threadIdx.x;
  if (e >= ETOT) return;
  int s, d; edge_sd(ei, e, s, d);
  float4 a = *(const float4*)(AS + (size_t)s * 4);
  float4 b = *(const float4*)(AD + (size_t)d * 4);
  float l0 = a.x + b.x, l1 = a.y + b.y, l2 = a.z + b.z, l3 = a.w + b.w;
  l0 = fmaxf(l0, SLOPE * l0); l1 = fmaxf(l1, SLOPE * l1);
  l2 = fmaxf(l2, SLOPE * l2); l3 = fmaxf(l3, SLOPE * l3);
  atomicMax(LM + (size_t)d * 4 + 0, f2key(l0));
  atomicMax(LM + (size_t)d * 4 + 1, f2key(l1));
  atomicMax(LM + (size_t)d * 4 + 2, f2key(l2));
  atomicMax(LM + (size_t)d * 4 + 3, f2key(l3));
}

// ---- per-edge exp(logit - max) -> segment sum ----
__global__ __launch_bounds__(256)
void edge_expsum(const int* __restrict__ ei, const float* __restrict__ AS,
                 const float* __restrict__ AD, const unsigned* __restrict__ LM,
                 float* __restrict__ DEN) {
  int e = blockIdx.x * 256 + threadIdx.x;
  if (e >= ETOT) return;
  int s, d; edge_sd(ei, e, s, d);
  float4 a = *(const float4*)(AS + (size_t)s * 4);
  float4 b = *(const float4*)(AD + (size_t)d * 4);
  const unsigned* lm = LM + (size_t)d * 4;
  float l0 = a.x + b.x, l1 = a.y + b.y, l2 = a.z + b.z, l3 = a.w + b.w;
  l0 = fmaxf(l0, SLOPE * l0); l1 = fmaxf(l1, SLOPE * l1);
  l2 = fmaxf(l2, SLOPE * l2); l3 = fmaxf(l3, SLOPE * l3);
  atomicAdd(DEN + (size_t)d * 4 + 0, __expf(l0 - key2f(lm[0])) );
  atomicAdd(DEN + (size_t)d * 4 + 1, __expf(l1 - key2f(lm[1])) );
  atomicAdd(DEN + (size_t)d * 4 + 2, __expf(l2 - key2f(lm[2])) );
  atomicAdd(DEN + (size_t)d * 4 + 3, __expf(l3 - key2f(lm[3])) );
}

// ---- message aggregation: out[dst] += alpha * xp[src] ----
// 128 threads per edge (one per column), 2 edges per 256-thread block.
__global__ __launch_bounds__(256)
void edge_aggregate(const int* __restrict__ ei, const float* __restrict__ AS,
                    const float* __restrict__ AD, const unsigned* __restrict__ LM,
                    const float* __restrict__ DEN, const float* __restrict__ XP,
                    float* __restrict__ OUT) {
  int e = blockIdx.x * 2 + (threadIdx.x >> 7);
  if (e >= ETOT) return;
  int c = threadIdx.x & 127;
  int h = c >> 5;
  int s, d; edge_sd(ei, e, s, d);
  float l = AS[(size_t)s * 4 + h] + AD[(size_t)d * 4 + h];
  l = fmaxf(l, SLOPE * l);
  float lm = key2f(LM[(size_t)d * 4 + h]);
  float alpha = __expf(l - lm) / (DEN[(size_t)d * 4 + h] + 1e-16f);
  atomicAdd(OUT + (size_t)d * HC + c, alpha * XP[(size_t)s * HC + c]);
}

// ---- out = relu(out + b) in place ----
__global__ __launch_bounds__(256)
void bias_relu(float* __restrict__ OUT, const float* __restrict__ B) {
  size_t i = (size_t)blockIdx.x * 256 + threadIdx.x;
  if (i >= (size_t)NN * HC) return;
  OUT[i] = fmaxf(OUT[i] + B[i & 127], 0.f);
}

// ---- final root gather + bias (no relu) ----
__global__ __launch_bounds__(256)
void gather_bias(const float* __restrict__ SRC, const int* __restrict__ ROOT,
                 const float* __restrict__ B, float* __restrict__ OUT,
                 int n_out) {
  int i = blockIdx.x * 256 + threadIdx.x;
  if (i >= n_out) return;
  int r = ROOT[i >> 7];
  int c = i & 127;
  OUT[i] = SRC[(size_t)r * HC + c] + B[c];
}

extern "C" void kernel_launch(void* const* d_in, const int* in_sizes, int n_in,
                              void* d_out, int out_size, void* d_ws, size_t ws_size,
                              hipStream_t stream) {
  const float* x    = (const float*)d_in[0];
  const int*   ei   = (const int*)d_in[1];
  const int*   root = (const int*)d_in[2];
  const float* W1   = (const float*)d_in[3];
  const float* as1  = (const float*)d_in[4];
  const float* ad1  = (const float*)d_in[5];
  const float* b1   = (const float*)d_in[6];
  const float* W2   = (const float*)d_in[7];
  const float* as2  = (const float*)d_in[8];
  const float* ad2  = (const float*)d_in[9];
  const float* b2   = (const float*)d_in[10];
  float* out = (float*)d_out;

  // workspace layout
  float*    A   = (float*)d_ws;                    // xp buffer   [NN*HC]
  float*    Bb  = A + (size_t)NN * HC;             // acc/h buffer[NN*HC]
  float*    AS  = Bb + (size_t)NN * HC;            // [NN*4]
  float*    AD  = AS + (size_t)NN * 4;             // [NN*4]
  unsigned* LM  = (unsigned*)(AD + (size_t)NN * 4);// [NN*4]
  float*    DEN = (float*)(LM + (size_t)NN * 4);   // [NN*4]

  const int edge_blocks = (ETOT + 255) / 256;
  const int agg_blocks  = (ETOT + 1) / 2;

  // ---------------- layer 1 ----------------
  gemm_alpha<256><<<NN / 8, 128, 0, stream>>>(x, W1, as1, ad1, A, AS, AD);
  hipMemsetAsync(LM, 0, (size_t)NN * 4 * 4, stream);
  hipMemsetAsync(DEN, 0, (size_t)NN * 4 * 4, stream);
  hipMemsetAsync(Bb, 0, (size_t)NN * HC * 4, stream);
  edge_max<<<edge_blocks, 256, 0, stream>>>(ei, AS, AD, LM);
  edge_expsum<<<edge_blocks, 256, 0, stream>>>(ei, AS, AD, LM, DEN);
  edge_aggregate<<<agg_blocks, 256, 0, stream>>>(ei, AS, AD, LM, DEN, A, Bb);
  bias_relu<<<((size_t)NN * HC + 255) / 256, 256, 0, stream>>>(Bb, b1);

  // ---------------- layer 2 ----------------
  gemm_alpha<128><<<NN / 8, 128, 0, stream>>>(Bb, W2, as2, ad2, A, AS, AD);
  hipMemsetAsync(LM, 0, (size_t)NN * 4 * 4, stream);
  hipMemsetAsync(DEN, 0, (size_t)NN * 4 * 4, stream);
  hipMemsetAsync(Bb, 0, (size_t)NN * HC * 4, stream);
  edge_max<<<edge_blocks, 256, 0, stream>>>(ei, AS, AD, LM);
  edge_expsum<<<edge_blocks, 256, 0, stream>>>(ei, AS, AD, LM, DEN);
  edge_aggregate<<<agg_blocks, 256, 0, stream>>>(ei, AS, AD, LM, DEN, A, Bb);

  // ---------------- output ----------------
  gather_bias<<<(out_size + 255) / 256, 256, 0, stream>>>(Bb, root, b2, out,
                                                          out_size);
}

// Round 2
// 412.870 us; speedup vs baseline: 3.8474x; 3.8474x over previous
//
#include <hip/hip_runtime.h>
#include <cstdint>
#include <cstddef>

// Problem constants (from reference)
constexpr int NN   = 50000;          // nodes
constexpr int EE   = 800000;         // edges (before self-loops)
constexpr int ETOT = EE + NN;        // edges + self loops
constexpr int HC   = 128;            // heads * per-head channels
constexpr float SLOPE = 0.2f;        // leaky_relu slope
constexpr int NB   = (NN + 255) / 256;  // scan blocks = 196

// ---------------------------------------------------------------------------
// fused GEMM (xp = X @ W) + per-node attention coefficients
// Block: 128 threads (one per output col). Each block does 8 rows.
// ---------------------------------------------------------------------------
template <int K>
__global__ __launch_bounds__(128)
void gemm_alpha(const float* __restrict__ X, const float* __restrict__ W,
                const float* __restrict__ atts, const float* __restrict__ attd,
                float* __restrict__ XP, float* __restrict__ AS,
                float* __restrict__ AD) {
  __shared__ float xs[8][K];
  const int c = threadIdx.x;              // 0..127 output column
  const int row0 = blockIdx.x * 8;
  #pragma unroll
  for (int r = 0; r < 8; ++r)
    for (int k = c; k < K; k += 128)
      xs[r][k] = X[(size_t)(row0 + r) * K + k];
  __syncthreads();

  float acc[8];
  #pragma unroll
  for (int r = 0; r < 8; ++r) acc[r] = 0.f;
  for (int k = 0; k < K; ++k) {
    float w = W[k * HC + c];              // coalesced, L2-resident
    #pragma unroll
    for (int r = 0; r < 8; ++r) acc[r] += xs[r][k] * w;
  }

  const float asc = atts[c];
  const float adc = attd[c];
  #pragma unroll
  for (int r = 0; r < 8; ++r) {
    XP[(size_t)(row0 + r) * HC + c] = acc[r];
    float s = acc[r] * asc;
    float d = acc[r] * adc;
    #pragma unroll
    for (int off = 16; off; off >>= 1) {  // reduce within one 32-lane head
      s += __shfl_xor(s, off);
      d += __shfl_xor(d, off);
    }
    if ((c & 31) == 0) {
      AS[(row0 + r) * 4 + (c >> 5)] = s;
      AD[(row0 + r) * 4 + (c >> 5)] = d;
    }
  }
}

// ---------------------------------------------------------------------------
// CSR build: histogram -> scan -> scatter (per call; ws is re-poisoned)
// ---------------------------------------------------------------------------
__device__ __forceinline__ void edge_sd(const int* __restrict__ ei, int e,
                                        int& s, int& d) {
  if (e < EE) { s = ei[e]; d = ei[EE + e]; }
  else        { s = e - EE; d = s; }      // self loop
}

__global__ __launch_bounds__(256)
void hist_kernel(const int* __restrict__ ei, int* __restrict__ deg) {
  int e = blockIdx.x * 256 + threadIdx.x;
  if (e >= ETOT) return;
  int s, d; edge_sd(ei, e, s, d);
  atomicAdd(deg + d, 1);
}

__global__ __launch_bounds__(256)
void scan_block(const int* __restrict__ deg, int* __restrict__ off,
                int* __restrict__ bsum) {
  __shared__ int tmp[256];
  const int tid = threadIdx.x;
  const int i = blockIdx.x * 256 + tid;
  int v = (i < NN) ? deg[i] : 0;
  tmp[tid] = v;
  __syncthreads();
  for (int d = 1; d < 256; d <<= 1) {     // inclusive Hillis-Steele
    int t = (tid >= d) ? tmp[tid - d] : 0;
    __syncthreads();
    tmp[tid] += t;
    __syncthreads();
  }
  if (i < NN) off[i] = tmp[tid] - v;      // exclusive within block
  if (tid == 255) bsum[blockIdx.x] = tmp[255];
}

__global__ __launch_bounds__(256)
void scan_top(int* __restrict__ bsum) {
  __shared__ int tmp[256];
  const int tid = threadIdx.x;
  int v = (tid < NB) ? bsum[tid] : 0;
  tmp[tid] = v;
  __syncthreads();
  for (int d = 1; d < 256; d <<= 1) {
    int t = (tid >= d) ? tmp[tid - d] : 0;
    __syncthreads();
    tmp[tid] += t;
    __syncthreads();
  }
  if (tid < NB) bsum[tid] = tmp[tid] - v; // exclusive block bases
}

__global__ __launch_bounds__(256)
void scan_add(int* __restrict__ off, const int* __restrict__ bsum) {
  int i = blockIdx.x * 256 + threadIdx.x;
  if (i < NN) off[i] += bsum[i >> 8];
  if (i == 0) off[NN] = ETOT;
}

__global__ __launch_bounds__(256)
void scatter_kernel(const int* __restrict__ ei, const int* __restrict__ off,
                    int* __restrict__ cnt, int* __restrict__ csr) {
  int e = blockIdx.x * 256 + threadIdx.x;
  if (e >= ETOT) return;
  int s, d; edge_sd(ei, e, s, d);
  int pos = off[d] + atomicAdd(cnt + d, 1);
  csr[pos] = s;
}

// ---------------------------------------------------------------------------
// Gather-side aggregation: one 128-thread block per destination node.
// Phase 1: per-head max (computed redundantly per wave, shfl reduce)
// Phase 2: per-head denominator (same pattern)
// Phase 3: chunked weighted accumulation with one coalesced XP row per edge
// Epilogue: /den + bias (+relu for layer 1). ROOT variant indexes root list
// and writes the final output rows directly.
// ---------------------------------------------------------------------------
__device__ __forceinline__ float4 leaky4(float4 a, float4 b) {
  float4 l;
  l.x = a.x + b.x; l.y = a.y + b.y; l.z = a.z + b.z; l.w = a.w + b.w;
  l.x = fmaxf(l.x, SLOPE * l.x); l.y = fmaxf(l.y, SLOPE * l.y);
  l.z = fmaxf(l.z, SLOPE * l.z); l.w = fmaxf(l.w, SLOPE * l.w);
  return l;
}

template <bool ROOT>
__global__ __launch_bounds__(128)
void aggregate(const int* __restrict__ roots, const int* __restrict__ off,
               const int* __restrict__ csr, const float* __restrict__ AS,
               const float* __restrict__ AD, const float* __restrict__ XP,
               const float* __restrict__ Bv, float* __restrict__ OUT) {
  const int node = ROOT ? roots[blockIdx.x] : blockIdx.x;
  const int tid = threadIdx.x;
  const int lane = tid & 63;
  const int c = tid;
  const int h = c >> 5;
  const int beg = off[node];
  const int deg = off[node + 1] - beg;
  const float4 ad4 = *(const float4*)(AD + (size_t)node * 4);

  // ---- phase 1: per-head max (both waves compute identical result) ----
  float4 m = make_float4(-1e30f, -1e30f, -1e30f, -1e30f);
  for (int i = lane; i < deg; i += 64) {
    int s = csr[beg + i];
    float4 a = *(const float4*)(AS + (size_t)s * 4);
    float4 l = leaky4(a, ad4);
    m.x = fmaxf(m.x, l.x); m.y = fmaxf(m.y, l.y);
    m.z = fmaxf(m.z, l.z); m.w = fmaxf(m.w, l.w);
  }
  #pragma unroll
  for (int o = 32; o; o >>= 1) {
    m.x = fmaxf(m.x, __shfl_xor(m.x, o));
    m.y = fmaxf(m.y, __shfl_xor(m.y, o));
    m.z = fmaxf(m.z, __shfl_xor(m.z, o));
    m.w = fmaxf(m.w, __shfl_xor(m.w, o));
  }

  // ---- phase 2: per-head denominator ----
  float4 den = make_float4(0.f, 0.f, 0.f, 0.f);
  for (int i = lane; i < deg; i += 64) {
    int s = csr[beg + i];
    float4 a = *(const float4*)(AS + (size_t)s * 4);
    float4 l = leaky4(a, ad4);
    den.x += __expf(l.x - m.x); den.y += __expf(l.y - m.y);
    den.z += __expf(l.z - m.z); den.w += __expf(l.w - m.w);
  }
  #pragma unroll
  for (int o = 32; o; o >>= 1) {
    den.x += __shfl_xor(den.x, o);
    den.y += __shfl_xor(den.y, o);
    den.z += __shfl_xor(den.z, o);
    den.w += __shfl_xor(den.w, o);
  }

  // ---- phase 3: weighted accumulation ----
  __shared__ float4 wls[128];
  __shared__ int    sls[128];
  float acc = 0.f;
  for (int base = 0; base < deg; base += 128) {
    const int n = min(128, deg - base);
    if (tid < n) {
      int s = csr[beg + base + tid];
      float4 a = *(const float4*)(AS + (size_t)s * 4);
      float4 l = leaky4(a, ad4);
      float4 w;
      w.x = __expf(l.x - m.x); w.y = __expf(l.y - m.y);
      w.z = __expf(l.z - m.z); w.w = __expf(l.w - m.w);
      wls[tid] = w;
      sls[tid] = s;
    }
    __syncthreads();
    for (int e = 0; e < n; ++e) {
      float w = ((const float*)&wls[e])[h];       // LDS broadcast
      acc += w * XP[(size_t)sls[e] * HC + c];     // coalesced 512B row
    }
    __syncthreads();
  }

  const float dh = (h == 0) ? den.x : (h == 1) ? den.y : (h == 2) ? den.z
                                                                  : den.w;
  float r = acc / (dh + 1e-16f) + Bv[c];
  if (!ROOT) r = fmaxf(r, 0.f);
  const size_t orow = ROOT ? (size_t)blockIdx.x : (size_t)node;
  OUT[orow * HC + c] = r;
}

// ---------------------------------------------------------------------------
extern "C" void kernel_launch(void* const* d_in, const int* in_sizes, int n_in,
                              void* d_out, int out_size, void* d_ws, size_t ws_size,
                              hipStream_t stream) {
  const float* x    = (const float*)d_in[0];
  const int*   ei   = (const int*)d_in[1];
  const int*   root = (const int*)d_in[2];
  const float* W1   = (const float*)d_in[3];
  const float* as1  = (const float*)d_in[4];
  const float* ad1  = (const float*)d_in[5];
  const float* b1   = (const float*)d_in[6];
  const float* W2   = (const float*)d_in[7];
  const float* as2  = (const float*)d_in[8];
  const float* ad2  = (const float*)d_in[9];
  const float* b2   = (const float*)d_in[10];
  float* out = (float*)d_out;

  // workspace layout
  float* XP  = (float*)d_ws;                       // [NN*HC]
  float* Hb  = XP + (size_t)NN * HC;               // [NN*HC]
  float* AS  = Hb + (size_t)NN * HC;               // [NN*4]
  float* AD  = AS + (size_t)NN * 4;                // [NN*4]
  int*   off = (int*)(AD + (size_t)NN * 4);        // [NN+1]
  int*   deg = off + (NN + 1);                     // [NN]
  int*   cnt = deg + NN;                           // [NN]
  int*   bsum= cnt + NN;                           // [256]
  int*   csr = bsum + 256;                         // [ETOT]

  const int eblocks = (ETOT + 255) / 256;

  // ---- CSR build (shared by both layers) ----
  hipMemsetAsync(deg, 0, (size_t)NN * 4, stream);
  hipMemsetAsync(cnt, 0, (size_t)NN * 4, stream);
  hist_kernel<<<eblocks, 256, 0, stream>>>(ei, deg);
  scan_block<<<NB, 256, 0, stream>>>(deg, off, bsum);
  scan_top<<<1, 256, 0, stream>>>(bsum);
  scan_add<<<NB, 256, 0, stream>>>(off, bsum);
  scatter_kernel<<<eblocks, 256, 0, stream>>>(ei, off, cnt, csr);

  // ---- layer 1 (all nodes) ----
  gemm_alpha<256><<<NN / 8, 128, 0, stream>>>(x, W1, as1, ad1, XP, AS, AD);
  aggregate<false><<<NN, 128, 0, stream>>>(nullptr, off, csr, AS, AD, XP, b1,
                                           Hb);

  // ---- layer 2 (aggregate only at the 1024 root nodes) ----
  gemm_alpha<128><<<NN / 8, 128, 0, stream>>>(Hb, W2, as2, ad2, XP, AS, AD);
  aggregate<true><<<out_size / HC, 128, 0, stream>>>(root, off, csr, AS, AD,
                                                     XP, b2, out);
}